// Round 1
// baseline (361.214 us; speedup 1.0000x reference)
//
#include <hip/hip_runtime.h>
#include <hip/hip_bf16.h>
#include <cstdint>
#include <cstddef>

#define D 128
#define SCAN_CHUNK 1024

typedef __attribute__((ext_vector_type(8))) __bf16 bf16v8;
typedef __attribute__((ext_vector_type(4))) float f32v4;

// Round-to-nearest-even fp32 -> bf16 (bits), packed pair.
__device__ inline unsigned int pack_bf16x2(float a, float b) {
  unsigned int ua = __float_as_uint(a);
  unsigned int ub = __float_as_uint(b);
  ua = (ua + 0x7fffu + ((ua >> 16) & 1u)) >> 16;
  ub = (ub + 0x7fffu + ((ub >> 16) & 1u)) >> 16;
  return ua | (ub << 16);
}
__device__ inline float bf_lo(unsigned int u) { return __uint_as_float(u << 16); }
__device__ inline float bf_hi(unsigned int u) { return __uint_as_float(u & 0xffff0000u); }

// ---------------------------------------------------------------------------
// Counting-sort pipeline: build dst-sorted CSR of (src, val) once per call.
// ---------------------------------------------------------------------------
__global__ __launch_bounds__(256) void hist_kernel(
    const int* __restrict__ dst, int* __restrict__ count, int E) {
  int e = blockIdx.x * 256 + threadIdx.x;
  if (e < E) atomicAdd(&count[dst[e]], 1);
}

__global__ __launch_bounds__(256) void scan_blocks(
    const int* __restrict__ count, int* __restrict__ rowptr,
    int* __restrict__ blockSums, int n) {
  __shared__ int sdata[256];
  const int tid = threadIdx.x;
  const int base = blockIdx.x * SCAN_CHUNK;
  int v[4];
#pragma unroll
  for (int k = 0; k < 4; ++k) {
    int idx = base + tid * 4 + k;
    v[k] = (idx < n) ? count[idx] : 0;
  }
  int s = v[0] + v[1] + v[2] + v[3];
  sdata[tid] = s;
  __syncthreads();
  for (int off = 1; off < 256; off <<= 1) {
    int x = (tid >= off) ? sdata[tid - off] : 0;
    __syncthreads();
    sdata[tid] += x;
    __syncthreads();
  }
  int run = sdata[tid] - s;
#pragma unroll
  for (int k = 0; k < 4; ++k) {
    int idx = base + tid * 4 + k;
    if (idx < n) rowptr[idx] = run;
    run += v[k];
  }
  if (tid == 255) blockSums[blockIdx.x] = sdata[255];
}

__global__ __launch_bounds__(256) void scan_top(int* __restrict__ bs, int nblk) {
  __shared__ int sdata[256];
  const int tid = threadIdx.x;
  int v[4];
#pragma unroll
  for (int k = 0; k < 4; ++k) {
    int idx = tid * 4 + k;
    v[k] = (idx < nblk) ? bs[idx] : 0;
  }
  int s = v[0] + v[1] + v[2] + v[3];
  sdata[tid] = s;
  __syncthreads();
  for (int off = 1; off < 256; off <<= 1) {
    int x = (tid >= off) ? sdata[tid - off] : 0;
    __syncthreads();
    sdata[tid] += x;
    __syncthreads();
  }
  int run = sdata[tid] - s;
#pragma unroll
  for (int k = 0; k < 4; ++k) {
    int idx = tid * 4 + k;
    if (idx < nblk) { int t = v[k]; bs[idx] = run; run += t; }
  }
}

__global__ __launch_bounds__(256) void add_offsets(
    int* __restrict__ rowptr, int* __restrict__ cursor,
    const int* __restrict__ bs, int n) {
  int i = blockIdx.x * 256 + threadIdx.x;
  if (i < n) {
    int v = rowptr[i] + bs[i >> 10];
    rowptr[i] = v;
    cursor[i] = v;
  }
}

__global__ __launch_bounds__(256) void scatter_edges(
    const int* __restrict__ src, const int* __restrict__ dst,
    const float* __restrict__ val, int* __restrict__ cursor,
    int2* __restrict__ sorted, int E) {
  int e = blockIdx.x * 256 + threadIdx.x;
  if (e < E) {
    int t = dst[e];
    int pos = atomicAdd(&cursor[t], 1);
    sorted[pos] = make_int2(src[e], __float_as_int(val[e]));
  }
}

// ---------------------------------------------------------------------------
// Weight cast: W (3 matrices, fp32 128x128) -> bf16, once per call.
// ---------------------------------------------------------------------------
__global__ __launch_bounds__(256) void cast_w(
    const float* __restrict__ W1, const float* __restrict__ W2,
    const float* __restrict__ W3, unsigned short* __restrict__ out) {
  const float* src[3] = {W1, W2, W3};
  int m = blockIdx.y;
  int i = blockIdx.x * 256 + threadIdx.x;
  if (i < D * D) {
    unsigned int u = __float_as_uint(src[m][i]);
    out[(size_t)m * D * D + i] =
        (unsigned short)((u + 0x7fffu + ((u >> 16) & 1u)) >> 16);
  }
}

// ---------------------------------------------------------------------------
// Dense transform Y = in @ W^T (bias/act fused into following SpMM).
// Round-5 form: BOTH H and W staged in LDS (W via strided-global reads in
// the MFMA loop regressed ~8us/dispatch in round 6 — gather-shaped B reads
// stall MFMA on vmcnt).
// ---------------------------------------------------------------------------
template <int F32IN>
__global__ __launch_bounds__(256) void dense_nt(
    const void* __restrict__ in_v, const unsigned short* __restrict__ Wb,
    unsigned short* __restrict__ out, int M) {
  __shared__ __align__(16) unsigned short Hs[128 * 136];
  __shared__ __align__(16) unsigned short Ws[128 * 136];

  const int tid = threadIdx.x;
  const int w = tid >> 6;
  const int lane = tid & 63;
  const int lane15 = lane & 15;
  const int quad = lane >> 4;
  const int row0 = blockIdx.x * 128;

  const uint4* w16 = (const uint4*)Wb;
#pragma unroll
  for (int it = 0; it < 8; ++it) {
    int c = it * 256 + tid;  // 0..2047
    int r = c >> 4;
    int ck = c & 15;
    *(uint4*)&Ws[r * 136 + ck * 8] = w16[(size_t)r * 16 + ck];
  }

  if (F32IN) {
    const float4* in32 = (const float4*)in_v;  // 32 chunks of 4 floats per row
#pragma unroll
    for (int it = 0; it < 16; ++it) {
      int c = it * 256 + tid;  // 0..4095
      int r = c >> 5;
      int ck = c & 31;
      float4 g = make_float4(0.f, 0.f, 0.f, 0.f);
      if (row0 + r < M) g = in32[(size_t)(row0 + r) * 32 + ck];
      uint2 pk = make_uint2(pack_bf16x2(g.x, g.y), pack_bf16x2(g.z, g.w));
      *(uint2*)&Hs[r * 136 + ck * 4] = pk;
    }
  } else {
    const uint4* in16 = (const uint4*)in_v;  // 16 chunks per bf16 row
#pragma unroll
    for (int it = 0; it < 8; ++it) {
      int c = it * 256 + tid;
      int r = c >> 4;
      int ck = c & 15;
      uint4 g = make_uint4(0, 0, 0, 0);
      if (row0 + r < M) g = in16[(size_t)(row0 + r) * 16 + ck];
      *(uint4*)&Hs[r * 136 + ck * 8] = g;
    }
  }
  __syncthreads();

  f32v4 acc[2][8];
#pragma unroll
  for (int mt = 0; mt < 2; ++mt)
#pragma unroll
    for (int nt = 0; nt < 8; ++nt) acc[mt][nt] = (f32v4){0.f, 0.f, 0.f, 0.f};

#pragma unroll
  for (int kt = 0; kt < 4; ++kt) {
    const int ko = kt * 32 + quad * 8;
    bf16v8 a0 = *(const bf16v8*)&Hs[(w * 32 + lane15) * 136 + ko];
    bf16v8 a1 = *(const bf16v8*)&Hs[(w * 32 + 16 + lane15) * 136 + ko];
#pragma unroll
    for (int nt = 0; nt < 8; ++nt) {
      bf16v8 b = *(const bf16v8*)&Ws[(nt * 16 + lane15) * 136 + ko];
      acc[0][nt] = __builtin_amdgcn_mfma_f32_16x16x32_bf16(a0, b, acc[0][nt], 0, 0, 0);
      acc[1][nt] = __builtin_amdgcn_mfma_f32_16x16x32_bf16(a1, b, acc[1][nt], 0, 0, 0);
    }
  }

#pragma unroll
  for (int mt = 0; mt < 2; ++mt) {
#pragma unroll
    for (int r = 0; r < 4; ++r) {
      int grow = row0 + w * 32 + mt * 16 + quad * 4 + r;
      if (grow < M) {
#pragma unroll
        for (int nt = 0; nt < 8; ++nt) {
          unsigned int u = __float_as_uint(acc[mt][nt][r]);
          out[(size_t)grow * D + nt * 16 + lane15] =
              (unsigned short)((u + 0x7fffu + ((u >> 16) & 1u)) >> 16);
        }
      }
    }
  }
}

// ---------------------------------------------------------------------------
// Fused SpMM, VALU-minimized form (round 7).
// One wave per row (wave-uniform via readfirstlane -> scalar rowptr/count).
// 16-lane groups: group g (of 4) processes edge k+g; lane l (of 16) owns
// dims 8l..8l+7 via ONE uint4 gather (16B x 16 lanes = full 256B row).
// The edge-record read is a single lane-indexed 8B load covering all 4
// groups' records (replaces 2 scalar-ish loads + half-select of round 6).
// Index clamp is a single v_min to the row's last edge (keeps masked lanes'
// gathers on already-fetched lines -> no extra FETCH); val masked to 0 past
// len. Addresses are 32-bit byte offsets off SGPR bases (global-saddr form,
// no 64-bit mul/addc chains). ~6 VALU/edge vs ~12.5 in round 6.
// Remainder loop (len>8, ~19% of rows at lambda=6.4) now retires 4
// edges/iteration instead of 1.
// MODE 0: bias+sigmoid -> bf16.  MODE 1: bias+row-softmax -> fp32.
// ---------------------------------------------------------------------------
template <int MODE>
__global__ __launch_bounds__(256) void spmm_fused(
    const unsigned int* __restrict__ h, const int2* __restrict__ sorted,
    const int* __restrict__ rowptr, const int* __restrict__ count,
    const float* __restrict__ bias, void* __restrict__ out_v, int n, int E) {
  const int wave = threadIdx.x >> 6;
  const int lane = threadIdx.x & 63;
  const int g = lane >> 4;   // edge group 0..3
  const int l = lane & 15;   // dim chunk: owns dims 8l..8l+7
  int row = blockIdx.x * 4 + wave;
  row = __builtin_amdgcn_readfirstlane(row);
  if (row >= n) return;
  int start = rowptr[row];
  const int len = count[row];
  const int lm1 = (len > 0) ? (len - 1) : 0;
  // Only len==0 trailing rows can have start==E; scalar clamp keeps record
  // reads in bounds (their val is masked to 0 anyway).
  if (start > E - 1) start = E - 1;

  const char* hb = (const char*)h;
  const char* sb = (const char*)sorted;
  const unsigned loff = (unsigned)l << 4;

  // hoisted: overlaps with the gathers below
  float4 bb0 = ((const float4*)bias)[2 * l];
  float4 bb1 = ((const float4*)bias)[2 * l + 1];

  float a0 = 0.f, a1 = 0.f, a2 = 0.f, a3 = 0.f;
  float a4 = 0.f, a5 = 0.f, a6 = 0.f, a7 = 0.f;

  // --- straight-line first 8 edges (2 iterations x 4 edges) ---
#pragma unroll
  for (int k = 0; k < 8; k += 4) {
    int kg = k + g;
    int i = (kg < lm1) ? kg : lm1;                       // v_min_i32
    int2 r = *(const int2*)(sb + ((unsigned)(start + i) << 3));
    float v = (kg < len) ? __int_as_float(r.y) : 0.f;    // v_cmp + cndmask
    uint4 u = *(const uint4*)(hb + (((unsigned)r.x << 8) + loff));
    a0 += v * bf_lo(u.x); a1 += v * bf_hi(u.x);
    a2 += v * bf_lo(u.y); a3 += v * bf_hi(u.y);
    a4 += v * bf_lo(u.z); a5 += v * bf_hi(u.z);
    a6 += v * bf_lo(u.w); a7 += v * bf_hi(u.w);
  }

  // --- remainder (len > 8), 4 edges/iteration ---
  for (int j = 8; j < len; j += 4) {
    int kg = j + g;
    int i = (kg < lm1) ? kg : lm1;
    int2 r = *(const int2*)(sb + ((unsigned)(start + i) << 3));
    float v = (kg < len) ? __int_as_float(r.y) : 0.f;
    uint4 u = *(const uint4*)(hb + (((unsigned)r.x << 8) + loff));
    a0 += v * bf_lo(u.x); a1 += v * bf_hi(u.x);
    a2 += v * bf_lo(u.y); a3 += v * bf_hi(u.y);
    a4 += v * bf_lo(u.z); a5 += v * bf_hi(u.z);
    a6 += v * bf_lo(u.w); a7 += v * bf_hi(u.w);
  }

  // Merge the 4 groups' partial sums (xor 16 then xor 32).
  a0 += __shfl_xor(a0, 16); a0 += __shfl_xor(a0, 32);
  a1 += __shfl_xor(a1, 16); a1 += __shfl_xor(a1, 32);
  a2 += __shfl_xor(a2, 16); a2 += __shfl_xor(a2, 32);
  a3 += __shfl_xor(a3, 16); a3 += __shfl_xor(a3, 32);
  a4 += __shfl_xor(a4, 16); a4 += __shfl_xor(a4, 32);
  a5 += __shfl_xor(a5, 16); a5 += __shfl_xor(a5, 32);
  a6 += __shfl_xor(a6, 16); a6 += __shfl_xor(a6, 32);
  a7 += __shfl_xor(a7, 16); a7 += __shfl_xor(a7, 32);

  a0 += bb0.x; a1 += bb0.y; a2 += bb0.z; a3 += bb0.w;
  a4 += bb1.x; a5 += bb1.y; a6 += bb1.z; a7 += bb1.w;

  if (MODE == 0) {
    if (g == 0) {
      uint4 pk;
      pk.x = pack_bf16x2(1.0f / (1.0f + __expf(-a0)), 1.0f / (1.0f + __expf(-a1)));
      pk.y = pack_bf16x2(1.0f / (1.0f + __expf(-a2)), 1.0f / (1.0f + __expf(-a3)));
      pk.z = pack_bf16x2(1.0f / (1.0f + __expf(-a4)), 1.0f / (1.0f + __expf(-a5)));
      pk.w = pack_bf16x2(1.0f / (1.0f + __expf(-a6)), 1.0f / (1.0f + __expf(-a7)));
      ((uint4*)out_v)[(size_t)row * 16 + l] = pk;
    }
  } else {
    float m = fmaxf(fmaxf(fmaxf(a0, a1), fmaxf(a2, a3)),
                    fmaxf(fmaxf(a4, a5), fmaxf(a6, a7)));
#pragma unroll
    for (int off = 8; off; off >>= 1) m = fmaxf(m, __shfl_xor(m, off));
    float e0 = __expf(a0 - m), e1 = __expf(a1 - m);
    float e2 = __expf(a2 - m), e3 = __expf(a3 - m);
    float e4 = __expf(a4 - m), e5 = __expf(a5 - m);
    float e6 = __expf(a6 - m), e7 = __expf(a7 - m);
    float s = ((e0 + e1) + (e2 + e3)) + ((e4 + e5) + (e6 + e7));
#pragma unroll
    for (int off = 8; off; off >>= 1) s += __shfl_xor(s, off);
    float inv = 1.0f / s;
    if (g == 0) {
      float4* o = (float4*)out_v + (size_t)row * 32 + 2 * l;
      o[0] = make_float4(e0 * inv, e1 * inv, e2 * inv, e3 * inv);
      o[1] = make_float4(e4 * inv, e5 * inv, e6 * inv, e7 * inv);
    }
  }
}

// ---------------------------------------------------------------------------
extern "C" void kernel_launch(void* const* d_in, const int* in_sizes, int n_in,
                              void* d_out, int out_size, void* d_ws, size_t ws_size,
                              hipStream_t stream) {
  const float* x  = (const float*)d_in[0];
  const float* ev = (const float*)d_in[1];
  const float* W1 = (const float*)d_in[2];
  const float* b1 = (const float*)d_in[3];
  const float* W2 = (const float*)d_in[4];
  const float* b2 = (const float*)d_in[5];
  const float* W3 = (const float*)d_in[6];
  const float* b3 = (const float*)d_in[7];
  const int* es = (const int*)d_in[8];
  const int* ed = (const int*)d_in[9];

  const int N = in_sizes[0] / D;
  const int E = in_sizes[1];

  // Workspace layout (all 16B-aligned)
  char* p = (char*)d_ws;
  unsigned int* BA = (unsigned int*)p; p += (size_t)N * 64 * sizeof(unsigned int);
  unsigned int* BB = (unsigned int*)p; p += (size_t)N * 64 * sizeof(unsigned int);
  int2* sorted = (int2*)p;          p += (size_t)E * sizeof(int2);
  unsigned short* Wb = (unsigned short*)p; p += 3 * (size_t)D * D * sizeof(unsigned short);
  int* count  = (int*)p;            p += (size_t)N * sizeof(int);
  int* rowptr = (int*)p;            p += (size_t)N * sizeof(int);
  int* cursor = (int*)p;            p += (size_t)N * sizeof(int);
  int* blockSums = (int*)p;         p += 1024 * sizeof(int);

  const int eblk = (E + 255) / 256;
  const int nblk256 = (N + 255) / 256;
  const int nblkScan = (N + SCAN_CHUNK - 1) / SCAN_CHUNK;
  const int rowgrid = (N + 3) / 4;
  const int dense_grid = (N + 127) / 128;

  // --- Build dst-sorted CSR + bf16 weights ---
  (void)hipMemsetAsync(count, 0, (size_t)N * sizeof(int), stream);
  hist_kernel<<<eblk, 256, 0, stream>>>(ed, count, E);
  cast_w<<<dim3((D * D + 255) / 256, 3), 256, 0, stream>>>(W1, W2, W3, Wb);
  scan_blocks<<<nblkScan, 256, 0, stream>>>(count, rowptr, blockSums, N);
  scan_top<<<1, 256, 0, stream>>>(blockSums, nblkScan);
  add_offsets<<<nblk256, 256, 0, stream>>>(rowptr, cursor, blockSums, N);
  scatter_edges<<<eblk, 256, 0, stream>>>(es, ed, ev, cursor, sorted, E);

  // --- Layer 1: Y1 = x@W1^T (fp32 in), h1 = sigmoid(A@Y1 + b1) ---
  dense_nt<1><<<dense_grid, 256, 0, stream>>>(x, Wb + 0 * D * D,
                                              (unsigned short*)BA, N);
  spmm_fused<0><<<rowgrid, 256, 0, stream>>>(BA, sorted, rowptr, count, b1, BB, N, E);
  // --- Layer 2 ---
  dense_nt<0><<<dense_grid, 256, 0, stream>>>(BB, Wb + 1 * D * D,
                                              (unsigned short*)BA, N);
  spmm_fused<0><<<rowgrid, 256, 0, stream>>>(BA, sorted, rowptr, count, b2, BB, N, E);
  // --- Layer 3: Y3 = h2@W3^T, out = softmax(A@Y3 + b3) ---
  dense_nt<0><<<dense_grid, 256, 0, stream>>>(BB, Wb + 2 * D * D,
                                              (unsigned short*)BA, N);
  spmm_fused<1><<<rowgrid, 256, 0, stream>>>(BA, sorted, rowptr, count, b3, d_out, N, E);
}